// Round 9
// baseline (284.295 us; speedup 1.0000x reference)
//
#include <hip/hip_runtime.h>

#define FEAT 64
#define HDIM 128
#define BN_EPS 1e-5f

#define BSH 7          // 128 nodes per kda block
#define SCHUNK 2048    // edges per scatter block (586 blocks)
#define NCAP 64        // slots per node (mean deg 12, +15 sigma)

// ws float offsets
#define PSOFF 1280     // column-major stats partials: pS[col][1024]
#define PQOFF (PSOFF + 65536)
#define WCOFF (PQOFF + 65536)
#define XNOFF (WCOFF + 8192)

typedef __attribute__((ext_vector_type(8))) short bf16x8;
typedef __attribute__((ext_vector_type(4))) float f32x4;

// async global->LDS, 16B per lane; LDS dest must be wave-uniform base
#define GL16(gp, lp)                                                        \
    __builtin_amdgcn_global_load_lds(                                       \
        (const __attribute__((address_space(1))) unsigned int*)(gp),        \
        (__attribute__((address_space(3))) unsigned int*)(lp), 16, 0, 0)

__device__ inline unsigned short f2bf(float f) {
    union { float f; unsigned int u; } v;
    v.f = f;
    unsigned int r = (v.u + 0x7FFFu + ((v.u >> 16) & 1u)) >> 16;  // RNE
    return (unsigned short)r;
}
__device__ inline float bf2f(unsigned short b) {
    union { unsigned int u; float f; } v;
    v.u = ((unsigned int)b) << 16;
    return v.f;
}

// ---------------- KA: edge scatter (CSR slots) | stats partials | Wc pack ---
// blocks [0,sbin): phase-free scatter — per edge: slot=atomicAdd(deg[dst]),
//   pairs[dst*64+slot]=src. No LDS, no barriers, 8 independent edges/thread.
//   (Replaces the 3-phase LDS-histogram scatter that was pinned at ~47 us.)
// blocks [sbin, sbin+1024): column sums/sumsq over contiguous row range.
// blocks [sbin+1024, sbin+1088): weight pack (MFMA fragment order).
// deg pre-zeroed by hipMemsetAsync.
__global__ __launch_bounds__(256) void kA(const float* __restrict__ x,
                                          float* __restrict__ ws,
                                          const float* __restrict__ Wl,
                                          const float* __restrict__ Wr,
                                          unsigned short* __restrict__ Wc,
                                          const int* __restrict__ ei,
                                          int* __restrict__ deg,
                                          int* __restrict__ pairs,
                                          int N, int E, int sbin) {
    __shared__ float4 sS[4][16];
    __shared__ float4 sQ[4][16];
    int blk = blockIdx.x, t = threadIdx.x;
    if (blk < sbin) {
        int e0 = blk * SCHUNK;
#pragma unroll
        for (int i = 0; i < SCHUNK / 256; i++) {
            int e = e0 + i * 256 + t;
            if (e < E) {
                int dst = ei[E + e];
                int slot = atomicAdd(&deg[dst], 1);
                if (slot < NCAP) pairs[(size_t)dst * NCAP + slot] = ei[e];
            }
        }
    } else if (blk < sbin + 1024) {
        int sblk = blk - sbin;
        int rpb = (N + 1023) >> 10;        // rows per stats block
        int colg = t & 15, rowi = t >> 4;  // 16 colgroups x 16 rows
        int lane = t & 63, wv = t >> 6;
        const float4* x4 = (const float4*)x;
        float4 s4 = {0.f, 0.f, 0.f, 0.f}, q4 = {0.f, 0.f, 0.f, 0.f};
        int r0 = sblk * rpb;
        for (int i = rowi; i < rpb; i += 16) {
            int r = r0 + i;
            if (r < N) {
                float4 v = x4[r * 16 + colg];
                s4.x += v.x; s4.y += v.y; s4.z += v.z; s4.w += v.w;
                q4.x += v.x * v.x; q4.y += v.y * v.y;
                q4.z += v.z * v.z; q4.w += v.w * v.w;
            }
        }
#pragma unroll
        for (int mk = 16; mk <= 32; mk <<= 1) {
            s4.x += __shfl_xor(s4.x, mk); s4.y += __shfl_xor(s4.y, mk);
            s4.z += __shfl_xor(s4.z, mk); s4.w += __shfl_xor(s4.w, mk);
            q4.x += __shfl_xor(q4.x, mk); q4.y += __shfl_xor(q4.y, mk);
            q4.z += __shfl_xor(q4.z, mk); q4.w += __shfl_xor(q4.w, mk);
        }
        if (lane < 16) { sS[wv][lane] = s4; sQ[wv][lane] = q4; }
        __syncthreads();
        if (t < 16) {
            float4 a = sS[0][t], b4 = sQ[0][t];
#pragma unroll
            for (int w = 1; w < 4; w++) {
                a.x += sS[w][t].x; a.y += sS[w][t].y;
                a.z += sS[w][t].z; a.w += sS[w][t].w;
                b4.x += sQ[w][t].x; b4.y += sQ[w][t].y;
                b4.z += sQ[w][t].z; b4.w += sQ[w][t].w;
            }
            int c0 = t * 4;
            ws[PSOFF + (c0 + 0) * 1024 + sblk] = a.x;
            ws[PSOFF + (c0 + 1) * 1024 + sblk] = a.y;
            ws[PSOFF + (c0 + 2) * 1024 + sblk] = a.z;
            ws[PSOFF + (c0 + 3) * 1024 + sblk] = a.w;
            ws[PQOFF + (c0 + 0) * 1024 + sblk] = b4.x;
            ws[PQOFF + (c0 + 1) * 1024 + sblk] = b4.y;
            ws[PQOFF + (c0 + 2) * 1024 + sblk] = b4.z;
            ws[PQOFF + (c0 + 3) * 1024 + sblk] = b4.w;
        }
    } else {
        int id = (blk - sbin - 1024) * 256 + t;  // 16384 total
        int n = id >> 7, k = id & 127;
        float w = (k < 64) ? Wl[k * HDIM + n] : Wr[(k - 64) * HDIM + n];
        Wc[((k >> 5) * 128 + n) * 32 + (k & 31)] = f2bf(w);
    }
}

// ---------------- KB: BN finalize (64 blocks, one column each) --------------
__global__ __launch_bounds__(256) void kB(float* __restrict__ ws,
                                          const float* __restrict__ gamma,
                                          const float* __restrict__ beta, int N) {
    __shared__ float r1[256], r2[256];
    int blk = blockIdx.x, t = threadIdx.x;
    const float* pS = ws + PSOFF + blk * 1024;
    const float* pQ = ws + PQOFF + blk * 1024;
    float s = 0.f, q = 0.f;
    for (int j = t; j < 1024; j += 256) { s += pS[j]; q += pQ[j]; }
    r1[t] = s;
    r2[t] = q;
    __syncthreads();
    for (int off = 128; off > 0; off >>= 1) {
        if (t < off) { r1[t] += r1[t + off]; r2[t] += r2[t + off]; }
        __syncthreads();
    }
    if (t == 0) {
        float invN = 1.0f / (float)N;
        float mean = r1[0] * invN;
        float var = r2[0] * invN - mean * mean;
        float sc = rsqrtf(var + BN_EPS) * gamma[blk];
        ws[128 + blk] = sc;
        ws[192 + blk] = beta[blk] - mean * sc;
    }
}

// ---------------- K3: xn = bf16(x*scale + shift) ----------------
__global__ __launch_bounds__(256) void k3_norm(const float* __restrict__ x,
                                               const float* __restrict__ ws,
                                               unsigned short* __restrict__ xn, int N) {
    const float4* x4 = (const float4*)x;
    ushort4* o4 = (ushort4*)xn;
    int n4 = N * (FEAT / 4);
    int stride = gridDim.x * blockDim.x;
    for (int i = blockIdx.x * blockDim.x + threadIdx.x; i < n4; i += stride) {
        int cg = (i & 15) << 2;
        float4 v = x4[i];
        float4 sc = *(const float4*)(ws + 128 + cg);
        float4 sh = *(const float4*)(ws + 192 + cg);
        ushort4 o;
        o.x = f2bf(v.x * sc.x + sh.x);
        o.y = f2bf(v.y * sc.y + sh.y);
        o.z = f2bf(v.z * sc.z + sh.z);
        o.w = f2bf(v.w * sc.w + sh.w);
        o4[i] = o;
    }
}

// ---------------- KDA: gather + mean straight from CSR slots ----------------
// No grouping phases (the per-node slots ARE the grouping): wave owns 16
// nodes (A=slot, B=slot+8); per-lane dependent chain pairs[node*64+e] ->
// xn[src]; unroll x2 -> 4 chains in flight. Zero LDS.
__global__ __launch_bounds__(512) void kda(const int* __restrict__ pairs,
                                           const int* __restrict__ degG,
                                           const unsigned short* __restrict__ xn,
                                           unsigned short* __restrict__ agg, int N) {
    int b = blockIdx.x;
    int base = b << BSH;
    int t = threadIdx.x;
    int lane = t & 63, wv = t >> 6;   // wv 0..7
    int part = lane & 7, slot = lane >> 3;

    int nA = base + wv * 16 + slot;
    int nB = nA + 8;
    int dA = (nA < N) ? degG[nA] : 0;
    int dB = (nB < N) ? degG[nB] : 0;
    int sA = min(dA, NCAP), sB = min(dB, NCAP);
    // wave-uniform trip count
    int dmax = max(sA, sB);
#pragma unroll
    for (int mk = 8; mk <= 32; mk <<= 1) dmax = max(dmax, __shfl_xor(dmax, mk));

    const int* pA = pairs + (size_t)nA * NCAP;
    const int* pB = pairs + (size_t)nB * NCAP;
    float accA[8], accB[8];
#pragma unroll
    for (int j = 0; j < 8; j++) { accA[j] = 0.f; accB[j] = 0.f; }
    for (int e = 0; e < dmax; e += 2) {
        bool a0 = e < sA, b0 = e < sB;
        bool a1 = e + 1 < sA, b1 = e + 1 < sB;
        bf16x8 vA0 = {}, vB0 = {}, vA1 = {}, vB1 = {};
        if (a0) vA0 = *(const bf16x8*)(xn + ((size_t)pA[e] << 6) + part * 8);
        if (b0) vB0 = *(const bf16x8*)(xn + ((size_t)pB[e] << 6) + part * 8);
        if (a1) vA1 = *(const bf16x8*)(xn + ((size_t)pA[e + 1] << 6) + part * 8);
        if (b1) vB1 = *(const bf16x8*)(xn + ((size_t)pB[e + 1] << 6) + part * 8);
#pragma unroll
        for (int j = 0; j < 8; j++) {
            accA[j] += (a0 ? bf2f((unsigned short)vA0[j]) : 0.f) +
                       (a1 ? bf2f((unsigned short)vA1[j]) : 0.f);
            accB[j] += (b0 ? bf2f((unsigned short)vB0[j]) : 0.f) +
                       (b1 ? bf2f((unsigned short)vB1[j]) : 0.f);
        }
    }
    if (nA < N) {
        float dinv = (dA > 0) ? (1.0f / (float)dA) : 0.0f;
        union { bf16x8 v; unsigned short u[8]; } o;
#pragma unroll
        for (int j = 0; j < 8; j++) o.u[j] = f2bf(accA[j] * dinv);
        *(bf16x8*)(agg + (size_t)nA * FEAT + part * 8) = o.v;
    }
    if (nB < N) {
        float dinv = (dB > 0) ? (1.0f / (float)dB) : 0.0f;
        union { bf16x8 v; unsigned short u[8]; } o;
#pragma unroll
        for (int j = 0; j < 8; j++) o.u[j] = f2bf(accB[j] * dinv);
        *(bf16x8*)(agg + (size_t)nB * FEAT + part * 8) = o.v;
    }
}

// ---------------- K5: MFMA GEMM (bf16) + fused head ----------------
// Round-1 proven version: A-tile staged via global_load_lds (width 16),
// XOR-swizzled source + matching read swizzle; register head with 16-lane
// tree reduce. VGPR 64, 3 blocks/CU.
__global__ __launch_bounds__(256, 3) void k5_gemm(
    const unsigned short* __restrict__ agg, const unsigned short* __restrict__ xn,
    const unsigned short* __restrict__ Wc, const float* __restrict__ bl,
    const float* __restrict__ W1, const float* __restrict__ b1,
    const float* __restrict__ W2, const float* __restrict__ b2,
    float* __restrict__ out, int N) {
    __shared__ unsigned char tile[16384];  // [0,8192): agg rows, [8192,16384): xn rows
    __shared__ float hq[64][17];           // cross-ch partial buffer (+1 pad)
    int t = threadIdx.x;
    int lane = t & 63;
    int wv = t >> 6;
    int rh = wv & 1;
    int ch = wv >> 1;
    int c = lane & 15;
    int q = lane >> 4;
    int row0 = blockIdx.x * 64;

    // ---- stage A-tile: 4 global_load_lds per wave, swizzled source ----
    {
        int rrow = t >> 3;  // 0..31 (row within round)
        int sseg = t & 7;
#pragma unroll
        for (int r = 0; r < 2; r++) {
            int row = r * 32 + rrow;               // LDS row 0..63
            int grow = min(row0 + row, N - 1);     // tail clamp (outputs guarded)
            int seg = sseg ^ (row & 7);            // pre-swizzled source segment
            unsigned ldso = (unsigned)(r * 4096 + wv * 1024);  // wave-uniform dest
            GL16(agg + (size_t)grow * 64 + seg * 8, &tile[ldso]);
            GL16(xn + (size_t)grow * 64 + seg * 8, &tile[8192 + ldso]);
        }
    }
    __syncthreads();

    // ---- MFMA main: C[64x128] = [agg|xn] @ Wc ----
    f32x4 acc[2][4];
    f32x4 z = {0.f, 0.f, 0.f, 0.f};
#pragma unroll
    for (int rt = 0; rt < 2; rt++)
#pragma unroll
        for (int nt = 0; nt < 4; nt++) acc[rt][nt] = z;

#pragma unroll
    for (int kt = 0; kt < 4; kt++) {
        bf16x8 bfr[4];
#pragma unroll
        for (int nt = 0; nt < 4; nt++) {
            int col = ch * 64 + nt * 16 + c;
            bfr[nt] = *(const bf16x8*)(Wc + ((size_t)kt * 128 + col) * 32 + q * 8);
        }
        const unsigned char* abase = &tile[(kt < 2) ? 0 : 8192];
        int sg = (kt & 1) * 4 + q;
        bf16x8 af[2];
#pragma unroll
        for (int rt = 0; rt < 2; rt++) {
            int rowL = rh * 32 + rt * 16 + c;
            af[rt] = *(const bf16x8*)&abase[rowL * 128 + ((sg ^ (rowL & 7)) << 4)];
        }
#pragma unroll
        for (int rt = 0; rt < 2; rt++)
#pragma unroll
            for (int nt = 0; nt < 4; nt++)
                acc[rt][nt] = __builtin_amdgcn_mfma_f32_16x16x32_bf16(
                    af[rt], bfr[nt], acc[rt][nt], 0, 0, 0);
    }

    // ---- head: hoist this thread's 4 W1 rows (64 VGPR) + biases ----
    float bln[4];
    float4 w1v[4][4];
#pragma unroll
    for (int nt = 0; nt < 4; nt++) {
        int col = ch * 64 + nt * 16 + c;
        bln[nt] = bl[col];
        const float4* wp = (const float4*)(W1 + col * 16);
#pragma unroll
        for (int qq = 0; qq < 4; qq++) w1v[nt][qq] = wp[qq];
    }
    // lane c ends the tree-reduce owning output m = bitrev4(c)
    int m = ((c & 1) << 3) | ((c & 2) << 1) | ((c & 4) >> 1) | ((c & 8) >> 3);
    float b1v = b1[m];
    float w2x = W2[2 * m];
    float w2y = W2[2 * m + 1];

    float sv[2][4];
#pragma unroll
    for (int rt = 0; rt < 2; rt++) {
#pragma unroll
        for (int r = 0; r < 4; r++) {
            float tp[16];
#pragma unroll
            for (int j = 0; j < 16; j++) tp[j] = 0.f;
#pragma unroll
            for (int nt = 0; nt < 4; nt++) {
                float hv = fmaxf(acc[rt][nt][r] + bln[nt], 0.f);
#pragma unroll
                for (int qq = 0; qq < 4; qq++) {
                    tp[qq * 4 + 0] += hv * w1v[nt][qq].x;
                    tp[qq * 4 + 1] += hv * w1v[nt][qq].y;
                    tp[qq * 4 + 2] += hv * w1v[nt][qq].z;
                    tp[qq * 4 + 3] += hv * w1v[nt][qq].w;
                }
            }
            // tree-exchange reduce over the 16 c-lanes: 15 shuffles
            float u[8];
#pragma unroll
            for (int k = 0; k < 8; k++) {
                float keep = (c & 1) ? tp[k + 8] : tp[k];
                float send = (c & 1) ? tp[k] : tp[k + 8];
                u[k] = keep + __shfl_xor(send, 1);
            }
            float v4[4];
#pragma unroll
            for (int k = 0; k < 4; k++) {
                float keep = (c & 2) ? u[k + 4] : u[k];
                float send = (c & 2) ? u[k] : u[k + 4];
                v4[k] = keep + __shfl_xor(send, 2);
            }
            float w2v[2];
#pragma unroll
            for (int k = 0; k < 2; k++) {
                float keep = (c & 4) ? v4[k + 2] : v4[k];
                float send = (c & 4) ? v4[k] : v4[k + 2];
                w2v[k] = keep + __shfl_xor(send, 4);
            }
            {
                float keep = (c & 8) ? w2v[1] : w2v[0];
                float send = (c & 8) ? w2v[0] : w2v[1];
                sv[rt][r] = keep + __shfl_xor(send, 8);
            }
        }
    }

    // ---- combine ch-halves, apply b1/relu/W2/b2, store ----
    if (ch == 0) {
#pragma unroll
        for (int rt = 0; rt < 2; rt++)
#pragma unroll
            for (int r = 0; r < 4; r++)
                hq[rh * 32 + rt * 16 + q * 4 + r][m] = sv[rt][r];
    }
    __syncthreads();
    if (ch == 1) {
        float b2x = b2[0], b2y = b2[1];
#pragma unroll
        for (int rt = 0; rt < 2; rt++) {
#pragma unroll
            for (int r = 0; r < 4; r++) {
                int row = rh * 32 + rt * 16 + q * 4 + r;
                float tm = sv[rt][r] + hq[row][m] + b1v;
                tm = fmaxf(tm, 0.f);
                float o0 = tm * w2x;
                float o1 = tm * w2y;
#pragma unroll
                for (int mk = 1; mk < 16; mk <<= 1) {
                    o0 += __shfl_xor(o0, mk);
                    o1 += __shfl_xor(o1, mk);
                }
                if (c == 0) {
                    int rowg = row0 + row;
                    if (rowg < N) {
                        out[(size_t)rowg * 2 + 0] = o0 + b2x;
                        out[(size_t)rowg * 2 + 1] = o1 + b2y;
                    }
                }
            }
        }
    }
}

extern "C" void kernel_launch(void* const* d_in, const int* in_sizes, int n_in,
                              void* d_out, int out_size, void* d_ws, size_t ws_size,
                              hipStream_t stream) {
    const float* x = (const float*)d_in[0];
    const int* ei = (const int*)d_in[1];
    const float* gamma = (const float*)d_in[6];
    const float* beta = (const float*)d_in[7];
    const float* Wl = (const float*)d_in[8];
    const float* bl = (const float*)d_in[9];
    const float* Wr = (const float*)d_in[10];
    const float* W1 = (const float*)d_in[11];
    const float* b1 = (const float*)d_in[12];
    const float* W2 = (const float*)d_in[13];
    const float* b2 = (const float*)d_in[14];

    int N = in_sizes[0] / FEAT;   // 100000
    int E = in_sizes[1] / 2;      // 1200000
    int sbin = (E + SCHUNK - 1) / SCHUNK;  // 586 scatter chunks

    float* ws = (float*)d_ws;
    int* wsi = (int*)d_ws;
    int aggOff = XNOFF + N * 32;            // N*32 floats
    int degOff = aggOff + N * 32;           // N ints
    int pairsOff = (degOff + N + 63) & ~63; // N*NCAP ints

    unsigned short* xnp = (unsigned short*)(ws + XNOFF);
    unsigned short* aggp = (unsigned short*)(ws + aggOff);
    unsigned short* wcp = (unsigned short*)(ws + WCOFF);
    int* deg = wsi + degOff;
    int* pairs = wsi + pairsOff;

    float* out = (float*)d_out;

    hipMemsetAsync(deg, 0, (size_t)N * sizeof(int), stream);
    hipLaunchKernelGGL(kA, dim3(sbin + 1088), dim3(256), 0, stream,
                       x, ws, Wl, Wr, wcp, ei, deg, pairs, N, E, sbin);
    hipLaunchKernelGGL(kB, dim3(64), dim3(256), 0, stream, ws, gamma, beta, N);
    hipLaunchKernelGGL(k3_norm, dim3(2048), dim3(256), 0, stream, x, ws, xnp, N);
    hipLaunchKernelGGL(kda, dim3((N + 127) >> BSH), dim3(512), 0, stream,
                       pairs, deg, xnp, aggp, N);
    hipLaunchKernelGGL(k5_gemm, dim3((N + 63) / 64), dim3(256), 0, stream,
                       aggp, xnp, wcp, bl, W1, b1, W2, b2, out, N);
}

// Round 10
// 265.549 us; speedup vs baseline: 1.0706x; 1.0706x over previous
//
#include <hip/hip_runtime.h>

#define FEAT 64
#define HDIM 128
#define BN_EPS 1e-5f

#define BSH 7          // 128 nodes per bucket
#define NB_MAX 1024    // max buckets (N <= 131072)
#define SCHUNK 8192    // edges per hist/scatter chunk (147 chunks)
#define CST 256        // chunk stride in hg/cb (>= nchunk)
#define CAP 2048       // pairs slots per bucket (mean 1536, +13 sigma)

// ws float offsets
#define PSOFF 1280     // column-major stats partials: pS[col][1024]
#define PQOFF (PSOFF + 65536)
#define WCOFF (PQOFF + 65536)
#define XNOFF (WCOFF + 8192)

typedef __attribute__((ext_vector_type(8))) short bf16x8;
typedef __attribute__((ext_vector_type(4))) float f32x4;

// async global->LDS, 16B per lane; LDS dest must be wave-uniform base
#define GL16(gp, lp)                                                        \
    __builtin_amdgcn_global_load_lds(                                       \
        (const __attribute__((address_space(1))) unsigned int*)(gp),        \
        (__attribute__((address_space(3))) unsigned int*)(lp), 16, 0, 0)

__device__ inline unsigned short f2bf(float f) {
    union { float f; unsigned int u; } v;
    v.f = f;
    unsigned int r = (v.u + 0x7FFFu + ((v.u >> 16) & 1u)) >> 16;  // RNE
    return (unsigned short)r;
}
__device__ inline float bf2f(unsigned short b) {
    union { unsigned int u; float f; } v;
    v.u = ((unsigned int)b) << 16;
    return v.f;
}

// ---------------- KA: per-chunk histogram | stats partials | Wc pack --------
// blocks [0,sbin): count chunk's dst into LDS hist (LDS atomics only), write
//   private row hg[b*CST+c] — ZERO global atomics (the round-6..8 scatter was
//   pinned at ~47us by ~300 serialized same-address cursor atomics/bucket).
// blocks [sbin, sbin+1024): column sums/sumsq over contiguous row range.
// blocks [sbin+1024, sbin+1088): weight pack (MFMA fragment order).
__global__ __launch_bounds__(256) void kA(const float* __restrict__ x,
                                          float* __restrict__ ws,
                                          const float* __restrict__ Wl,
                                          const float* __restrict__ Wr,
                                          unsigned short* __restrict__ Wc,
                                          const int* __restrict__ ei,
                                          int* __restrict__ hg,
                                          int N, int E, int nb, int sbin) {
    __shared__ float4 sS[4][16];
    __shared__ float4 sQ[4][16];
    __shared__ int hist[NB_MAX];
    int blk = blockIdx.x, t = threadIdx.x;
    if (blk < sbin) {
        int c = blk;
        int e0 = c * SCHUNK;
        for (int b = t; b < NB_MAX; b += 256) hist[b] = 0;
        __syncthreads();
#pragma unroll
        for (int i = 0; i < SCHUNK / 256; i++) {
            int e = e0 + i * 256 + t;
            if (e < E) atomicAdd(&hist[((unsigned)ei[E + e]) >> BSH], 1);
        }
        __syncthreads();
        for (int b = t; b < nb; b += 256) hg[b * CST + c] = hist[b];
    } else if (blk < sbin + 1024) {
        int sblk = blk - sbin;
        int rpb = (N + 1023) >> 10;        // rows per stats block
        int colg = t & 15, rowi = t >> 4;  // 16 colgroups x 16 rows
        int lane = t & 63, wv = t >> 6;
        const float4* x4 = (const float4*)x;
        float4 s4 = {0.f, 0.f, 0.f, 0.f}, q4 = {0.f, 0.f, 0.f, 0.f};
        int r0 = sblk * rpb;
        for (int i = rowi; i < rpb; i += 16) {
            int r = r0 + i;
            if (r < N) {
                float4 v = x4[r * 16 + colg];
                s4.x += v.x; s4.y += v.y; s4.z += v.z; s4.w += v.w;
                q4.x += v.x * v.x; q4.y += v.y * v.y;
                q4.z += v.z * v.z; q4.w += v.w * v.w;
            }
        }
#pragma unroll
        for (int mk = 16; mk <= 32; mk <<= 1) {
            s4.x += __shfl_xor(s4.x, mk); s4.y += __shfl_xor(s4.y, mk);
            s4.z += __shfl_xor(s4.z, mk); s4.w += __shfl_xor(s4.w, mk);
            q4.x += __shfl_xor(q4.x, mk); q4.y += __shfl_xor(q4.y, mk);
            q4.z += __shfl_xor(q4.z, mk); q4.w += __shfl_xor(q4.w, mk);
        }
        if (lane < 16) { sS[wv][lane] = s4; sQ[wv][lane] = q4; }
        __syncthreads();
        if (t < 16) {
            float4 a = sS[0][t], b4 = sQ[0][t];
#pragma unroll
            for (int w = 1; w < 4; w++) {
                a.x += sS[w][t].x; a.y += sS[w][t].y;
                a.z += sS[w][t].z; a.w += sS[w][t].w;
                b4.x += sQ[w][t].x; b4.y += sQ[w][t].y;
                b4.z += sQ[w][t].z; b4.w += sQ[w][t].w;
            }
            int c0 = t * 4;
            ws[PSOFF + (c0 + 0) * 1024 + sblk] = a.x;
            ws[PSOFF + (c0 + 1) * 1024 + sblk] = a.y;
            ws[PSOFF + (c0 + 2) * 1024 + sblk] = a.z;
            ws[PSOFF + (c0 + 3) * 1024 + sblk] = a.w;
            ws[PQOFF + (c0 + 0) * 1024 + sblk] = b4.x;
            ws[PQOFF + (c0 + 1) * 1024 + sblk] = b4.y;
            ws[PQOFF + (c0 + 2) * 1024 + sblk] = b4.z;
            ws[PQOFF + (c0 + 3) * 1024 + sblk] = b4.w;
        }
    } else {
        int id = (blk - sbin - 1024) * 256 + t;  // 16384 total
        int n = id >> 7, k = id & 127;
        float w = (k < 64) ? Wl[k * HDIM + n] : Wr[(k - 64) * HDIM + n];
        Wc[((k >> 5) * 128 + n) * 32 + (k & 31)] = f2bf(w);
    }
}

// ---------------- KB: BN finalize | per-bucket chunk scan -------------------
// blocks [0,64): column c=blk reduce of 1024 partials -> scale/shift
// blocks [64,64+nsb): one WAVE per bucket — shfl-scan the 147 chunk counts
//   hg[b][*] -> exclusive bases cb[b][*] and bktTot[b]. No atomics.
__global__ __launch_bounds__(256) void kB(float* __restrict__ ws,
                                          const float* __restrict__ gamma,
                                          const float* __restrict__ beta,
                                          const int* __restrict__ hg,
                                          int* __restrict__ cb,
                                          int* __restrict__ bktTot,
                                          int N, int nb, int sbin) {
    int blk = blockIdx.x, t = threadIdx.x;
    if (blk < 64) {
        __shared__ float r1[256], r2[256];
        const float* pS = ws + PSOFF + blk * 1024;
        const float* pQ = ws + PQOFF + blk * 1024;
        float s = 0.f, q = 0.f;
        for (int j = t; j < 1024; j += 256) { s += pS[j]; q += pQ[j]; }
        r1[t] = s;
        r2[t] = q;
        __syncthreads();
        for (int off = 128; off > 0; off >>= 1) {
            if (t < off) { r1[t] += r1[t + off]; r2[t] += r2[t + off]; }
            __syncthreads();
        }
        if (t == 0) {
            float invN = 1.0f / (float)N;
            float mean = r1[0] * invN;
            float var = r2[0] * invN - mean * mean;
            float sc = rsqrtf(var + BN_EPS) * gamma[blk];
            ws[128 + blk] = sc;
            ws[192 + blk] = beta[blk] - mean * sc;
        }
    } else {
        int lane = t & 63, wv = t >> 6;
        int b = (blk - 64) * 4 + wv;  // bucket for this wave
        if (b >= nb) return;
        int running = 0;
        for (int t0 = 0; t0 < sbin; t0 += 64) {
            int c = t0 + lane;
            int v = (c < sbin) ? hg[b * CST + c] : 0;
            int incl = v;
#pragma unroll
            for (int off = 1; off < 64; off <<= 1) {
                int tv = __shfl_up(incl, off);
                if (lane >= off) incl += tv;
            }
            if (c < sbin) cb[b * CST + c] = running + incl - v;
            running += __shfl(incl, 63);
        }
        if (lane == 0) bktTot[b] = running;
    }
}

// ---------------- K3: normalize | deterministic scatter ---------------------
// blocks [0,2048): xn = bf16(x*scale + shift), float4 grid-stride.
// blocks [2048,2048+sbin): scatter chunk c — LDS-local cursors only; write
//   pairs[b*CAP + cb[b][c] + off]. Zero global atomics; bucket-contiguous runs.
__global__ __launch_bounds__(256) void k3_norm(const float* __restrict__ x,
                                               const float* __restrict__ ws,
                                               unsigned short* __restrict__ xn,
                                               const int* __restrict__ ei,
                                               const int* __restrict__ cb,
                                               int* __restrict__ pairs,
                                               int N, int E, int nb, int sbin) {
    __shared__ int lh[NB_MAX];
    __shared__ int cbL[NB_MAX];
    int blk = blockIdx.x, t = threadIdx.x;
    if (blk < 2048) {
        const float4* x4 = (const float4*)x;
        ushort4* o4 = (ushort4*)xn;
        int n4 = N * (FEAT / 4);
        int stride = 2048 * 256;
        for (int i = blk * 256 + t; i < n4; i += stride) {
            int cg = (i & 15) << 2;
            float4 v = x4[i];
            float4 sc = *(const float4*)(ws + 128 + cg);
            float4 sh = *(const float4*)(ws + 192 + cg);
            ushort4 o;
            o.x = f2bf(v.x * sc.x + sh.x);
            o.y = f2bf(v.y * sc.y + sh.y);
            o.z = f2bf(v.z * sc.z + sh.z);
            o.w = f2bf(v.w * sc.w + sh.w);
            o4[i] = o;
        }
    } else {
        int c = blk - 2048;
        int e0 = c * SCHUNK;
        for (int b = t; b < nb; b += 256) {
            lh[b] = 0;
            cbL[b] = cb[b * CST + c];
        }
        __syncthreads();
#pragma unroll
        for (int i = 0; i < SCHUNK / 256; i++) {
            int e = e0 + i * 256 + t;
            if (e < E) {
                int src = ei[e];
                int dst = ei[E + e];
                int b = ((unsigned)dst) >> BSH;
                int off = atomicAdd(&lh[b], 1);
                int rel = cbL[b] + off;
                if (rel < CAP) pairs[b * CAP + rel] = (src << BSH) | (dst & 127);
            }
        }
    }
}

// ---------------- KDA: fine-group (LDS) + gather + mean ----------------
// Round-2 proven version; bucket b occupies pairs[b*CAP .. b*CAP+bktTot[b]).
// sidx now CAP ints (8 KB) -> ~9.8 KB LDS, 4 blocks/CU = 32 waves (max occ).
__global__ __launch_bounds__(512) void kda(const int* __restrict__ pairs,
                                           const int* __restrict__ bktTot,
                                           const unsigned short* __restrict__ xn,
                                           unsigned short* __restrict__ agg, int N) {
    __shared__ int sidx[CAP];
    __shared__ int cnt[128], nstart[128], ncur[128];
    int b = blockIdx.x;
    int base = b << BSH;
    int total = min(bktTot[b], CAP);
    int bs = b * CAP, be = bs + total;
    int t = threadIdx.x;
    int lane = t & 63, wv = t >> 6;   // wv 0..7
    int part = lane & 7, slot = lane >> 3;

    if (t < 128) cnt[t] = 0;
    __syncthreads();
    for (int i = bs + t; i < be; i += 512)
        atomicAdd(&cnt[pairs[i] & 127], 1);
    __syncthreads();
    // wave-0 shuffle scan over the 128 counters
    if (wv == 0) {
        int c0 = cnt[lane], c1 = cnt[64 + lane];
        int a = c0, d = c1;
#pragma unroll
        for (int off = 1; off < 64; off <<= 1) {
            int ta = __shfl_up(a, off);
            int td = __shfl_up(d, off);
            if (lane >= off) { a += ta; d += td; }
        }
        int totA = __shfl(a, 63);
        d += totA;
        nstart[lane] = a - c0;
        ncur[lane] = a - c0;
        nstart[64 + lane] = d - c1;
        ncur[64 + lane] = d - c1;
    }
    __syncthreads();
    for (int i = bs + t; i < be; i += 512) {
        int p = pairs[i];
        int nid = p & 127;
        int pos = atomicAdd(&ncur[nid], 1);
        sidx[pos] = (p >> BSH) << 6;  // src row offset in ushorts
    }
    __syncthreads();

    // gather: wave owns 16 nodes = groups A (slot) and B (slot+8)
    int nA = wv * 16 + slot;
    int nB = nA + 8;
    int stA = nstart[nA], dA = cnt[nA];
    int stB = nstart[nB], dB = cnt[nB];
    float accA[8], accB[8];
#pragma unroll
    for (int j = 0; j < 8; j++) { accA[j] = 0.f; accB[j] = 0.f; }
    bf16x8 vA = {}, vB = {};
    for (int e = 0;; e++) {
        bool pA = e < dA, pB = e < dB;
        if (!__any(pA || pB)) break;
        if (pA) vA = *(const bf16x8*)(xn + sidx[stA + e] + part * 8);
        if (pB) vB = *(const bf16x8*)(xn + sidx[stB + e] + part * 8);
#pragma unroll
        for (int j = 0; j < 8; j++) {
            accA[j] += pA ? bf2f((unsigned short)vA[j]) : 0.f;
            accB[j] += pB ? bf2f((unsigned short)vB[j]) : 0.f;
        }
    }
    int nodeA = base + nA;
    int nodeB = base + nB;
    if (nodeA < N) {
        float dinv = (dA > 0) ? (1.0f / (float)dA) : 0.0f;
        union { bf16x8 v; unsigned short u[8]; } o;
#pragma unroll
        for (int j = 0; j < 8; j++) o.u[j] = f2bf(accA[j] * dinv);
        *(bf16x8*)(agg + (size_t)nodeA * FEAT + part * 8) = o.v;
    }
    if (nodeB < N) {
        float dinv = (dB > 0) ? (1.0f / (float)dB) : 0.0f;
        union { bf16x8 v; unsigned short u[8]; } o;
#pragma unroll
        for (int j = 0; j < 8; j++) o.u[j] = f2bf(accB[j] * dinv);
        *(bf16x8*)(agg + (size_t)nodeB * FEAT + part * 8) = o.v;
    }
}

// ---------------- K5: MFMA GEMM (bf16) + fused head ----------------
// Round-1 proven version: A-tile staged via global_load_lds (width 16),
// XOR-swizzled source + matching read swizzle; register head with 16-lane
// tree reduce. VGPR 64, 3 blocks/CU.
__global__ __launch_bounds__(256, 3) void k5_gemm(
    const unsigned short* __restrict__ agg, const unsigned short* __restrict__ xn,
    const unsigned short* __restrict__ Wc, const float* __restrict__ bl,
    const float* __restrict__ W1, const float* __restrict__ b1,
    const float* __restrict__ W2, const float* __restrict__ b2,
    float* __restrict__ out, int N) {
    __shared__ unsigned char tile[16384];  // [0,8192): agg rows, [8192,16384): xn rows
    __shared__ float hq[64][17];           // cross-ch partial buffer (+1 pad)
    int t = threadIdx.x;
    int lane = t & 63;
    int wv = t >> 6;
    int rh = wv & 1;
    int ch = wv >> 1;
    int c = lane & 15;
    int q = lane >> 4;
    int row0 = blockIdx.x * 64;

    // ---- stage A-tile: 4 global_load_lds per wave, swizzled source ----
    {
        int rrow = t >> 3;  // 0..31 (row within round)
        int sseg = t & 7;
#pragma unroll
        for (int r = 0; r < 2; r++) {
            int row = r * 32 + rrow;               // LDS row 0..63
            int grow = min(row0 + row, N - 1);     // tail clamp (outputs guarded)
            int seg = sseg ^ (row & 7);            // pre-swizzled source segment
            unsigned ldso = (unsigned)(r * 4096 + wv * 1024);  // wave-uniform dest
            GL16(agg + (size_t)grow * 64 + seg * 8, &tile[ldso]);
            GL16(xn + (size_t)grow * 64 + seg * 8, &tile[8192 + ldso]);
        }
    }
    __syncthreads();

    // ---- MFMA main: C[64x128] = [agg|xn] @ Wc ----
    f32x4 acc[2][4];
    f32x4 z = {0.f, 0.f, 0.f, 0.f};
#pragma unroll
    for (int rt = 0; rt < 2; rt++)
#pragma unroll
        for (int nt = 0; nt < 4; nt++) acc[rt][nt] = z;

#pragma unroll
    for (int kt = 0; kt < 4; kt++) {
        bf16x8 bfr[4];
#pragma unroll
        for (int nt = 0; nt < 4; nt++) {
            int col = ch * 64 + nt * 16 + c;
            bfr[nt] = *(const bf16x8*)(Wc + ((size_t)kt * 128 + col) * 32 + q * 8);
        }
        const unsigned char* abase = &tile[(kt < 2) ? 0 : 8192];
        int sg = (kt & 1) * 4 + q;
        bf16x8 af[2];
#pragma unroll
        for (int rt = 0; rt < 2; rt++) {
            int rowL = rh * 32 + rt * 16 + c;
            af[rt] = *(const bf16x8*)&abase[rowL * 128 + ((sg ^ (rowL & 7)) << 4)];
        }
#pragma unroll
        for (int rt = 0; rt < 2; rt++)
#pragma unroll
            for (int nt = 0; nt < 4; nt++)
                acc[rt][nt] = __builtin_amdgcn_mfma_f32_16x16x32_bf16(
                    af[rt], bfr[nt], acc[rt][nt], 0, 0, 0);
    }

    // ---- head: hoist this thread's 4 W1 rows (64 VGPR) + biases ----
    float bln[4];
    float4 w1v[4][4];
#pragma unroll
    for (int nt = 0; nt < 4; nt++) {
        int col = ch * 64 + nt * 16 + c;
        bln[nt] = bl[col];
        const float4* wp = (const float4*)(W1 + col * 16);
#pragma unroll
        for (int qq = 0; qq < 4; qq++) w1v[nt][qq] = wp[qq];
    }
    // lane c ends the tree-reduce owning output m = bitrev4(c)
    int m = ((c & 1) << 3) | ((c & 2) << 1) | ((c & 4) >> 1) | ((c & 8) >> 3);
    float b1v = b1[m];
    float w2x = W2[2 * m];
    float w2y = W2[2 * m + 1];

    float sv[2][4];
#pragma unroll
    for (int rt = 0; rt < 2; rt++) {
#pragma unroll
        for (int r = 0; r < 4; r++) {
            float tp[16];
#pragma unroll
            for (int j = 0; j < 16; j++) tp[j] = 0.f;
#pragma unroll
            for (int nt = 0; nt < 4; nt++) {
                float hv = fmaxf(acc[rt][nt][r] + bln[nt], 0.f);
#pragma unroll
                for (int qq = 0; qq < 4; qq++) {
                    tp[qq * 4 + 0] += hv * w1v[nt][qq].x;
                    tp[qq * 4 + 1] += hv * w1v[nt][qq].y;
                    tp[qq * 4 + 2] += hv * w1v[nt][qq].z;
                    tp[qq * 4 + 3] += hv * w1v[nt][qq].w;
                }
            }
            // tree-exchange reduce over the 16 c-lanes: 15 shuffles
            float u[8];
#pragma unroll
            for (int k = 0; k < 8; k++) {
                float keep = (c & 1) ? tp[k + 8] : tp[k];
                float send = (c & 1) ? tp[k] : tp[k + 8];
                u[k] = keep + __shfl_xor(send, 1);
            }
            float v4[4];
#pragma unroll
            for (int k = 0; k < 4; k++) {
                float keep = (c & 2) ? u[k + 4] : u[k];
                float send = (c & 2) ? u[k] : u[k + 4];
                v4[k] = keep + __shfl_xor(send, 2);
            }
            float w2v[2];
#pragma unroll
            for (int k = 0; k < 2; k++) {
                float keep = (c & 4) ? v4[k + 2] : v4[k];
                float send = (c & 4) ? v4[k] : v4[k + 2];
                w2v[k] = keep + __shfl_xor(send, 4);
            }
            {
                float keep = (c & 8) ? w2v[1] : w2v[0];
                float send = (c & 8) ? w2v[0] : w2v[1];
                sv[rt][r] = keep + __shfl_xor(send, 8);
            }
        }
    }

    // ---- combine ch-halves, apply b1/relu/W2/b2, store ----
    if (ch == 0) {
#pragma unroll
        for (int rt = 0; rt < 2; rt++)
#pragma unroll
            for (int r = 0; r < 4; r++)
                hq[rh * 32 + rt * 16 + q * 4 + r][m] = sv[rt][r];
    }
    __syncthreads();
    if (ch == 1) {
        float b2x = b2[0], b2y = b2[1];
#pragma unroll
        for (int rt = 0; rt < 2; rt++) {
#pragma unroll
            for (int r = 0; r < 4; r++) {
                int row = rh * 32 + rt * 16 + q * 4 + r;
                float tm = sv[rt][r] + hq[row][m] + b1v;
                tm = fmaxf(tm, 0.f);
                float o0 = tm * w2x;
                float o1 = tm * w2y;
#pragma unroll
                for (int mk = 1; mk < 16; mk <<= 1) {
                    o0 += __shfl_xor(o0, mk);
                    o1 += __shfl_xor(o1, mk);
                }
                if (c == 0) {
                    int rowg = row0 + row;
                    if (rowg < N) {
                        out[(size_t)rowg * 2 + 0] = o0 + b2x;
                        out[(size_t)rowg * 2 + 1] = o1 + b2y;
                    }
                }
            }
        }
    }
}

extern "C" void kernel_launch(void* const* d_in, const int* in_sizes, int n_in,
                              void* d_out, int out_size, void* d_ws, size_t ws_size,
                              hipStream_t stream) {
    const float* x = (const float*)d_in[0];
    const int* ei = (const int*)d_in[1];
    const float* gamma = (const float*)d_in[6];
    const float* beta = (const float*)d_in[7];
    const float* Wl = (const float*)d_in[8];
    const float* bl = (const float*)d_in[9];
    const float* Wr = (const float*)d_in[10];
    const float* W1 = (const float*)d_in[11];
    const float* b1 = (const float*)d_in[12];
    const float* W2 = (const float*)d_in[13];
    const float* b2 = (const float*)d_in[14];

    int N = in_sizes[0] / FEAT;   // 100000
    int E = in_sizes[1] / 2;      // 1200000
    int nb = (N + 127) >> BSH;    // 782 buckets
    int sbin = (E + SCHUNK - 1) / SCHUNK;  // 147 chunks
    int nsb = (nb + 3) / 4;                // scan blocks (4 waves each)

    float* ws = (float*)d_ws;
    int* wsi = (int*)d_ws;
    int aggOff = XNOFF + N * 32;             // N*32 floats (bf16 agg)
    int hgOff = aggOff + N * 32;             // NB_MAX*CST ints
    int cbOff = hgOff + NB_MAX * CST;        // NB_MAX*CST ints
    int btOff = cbOff + NB_MAX * CST;        // NB_MAX ints
    int pairsOff = (btOff + NB_MAX + 63) & ~63;  // nb*CAP ints

    unsigned short* xnp = (unsigned short*)(ws + XNOFF);
    unsigned short* aggp = (unsigned short*)(ws + aggOff);
    unsigned short* wcp = (unsigned short*)(ws + WCOFF);
    int* hg = wsi + hgOff;
    int* cb = wsi + cbOff;
    int* bktTot = wsi + btOff;
    int* pairs = wsi + pairsOff;

    float* out = (float*)d_out;

    hipLaunchKernelGGL(kA, dim3(sbin + 1088), dim3(256), 0, stream,
                       x, ws, Wl, Wr, wcp, ei, hg, N, E, nb, sbin);
    hipLaunchKernelGGL(kB, dim3(64 + nsb), dim3(256), 0, stream,
                       ws, gamma, beta, hg, cb, bktTot, N, nb, sbin);
    hipLaunchKernelGGL(k3_norm, dim3(2048 + sbin), dim3(256), 0, stream,
                       x, ws, xnp, ei, cb, pairs, N, E, nb, sbin);
    hipLaunchKernelGGL(kda, dim3(nb), dim3(512), 0, stream,
                       pairs, bktTot, xnp, aggp, N);
    hipLaunchKernelGGL(k5_gemm, dim3((N + 63) / 64), dim3(256), 0, stream,
                       aggp, xnp, wcp, bl, W1, b1, W2, b2, out, N);
}

// Round 11
// 249.408 us; speedup vs baseline: 1.1399x; 1.0647x over previous
//
#include <hip/hip_runtime.h>

#define FEAT 64
#define HDIM 128
#define BN_EPS 1e-5f

#define BSH 7          // 128 nodes per bucket
#define NB_MAX 1024    // max buckets (N <= 131072)
#define NBP 800        // padded bucket stride (chunk-major hg/cb rows)
#define SCHUNK 2048    // edges per hist/scatter chunk (586 chunks)
#define CMAX 640       // max chunks allocated
#define CAP 2048       // pairs slots per bucket (mean 1536, +13 sigma)

// ws float offsets
#define PSOFF 1280     // column-major stats partials: pS[col][1024]
#define PQOFF (PSOFF + 65536)
#define WCOFF (PQOFF + 65536)
#define XNOFF (WCOFF + 8192)

typedef __attribute__((ext_vector_type(8))) short bf16x8;
typedef __attribute__((ext_vector_type(4))) float f32x4;

// async global->LDS, 16B per lane; LDS dest must be wave-uniform base
#define GL16(gp, lp)                                                        \
    __builtin_amdgcn_global_load_lds(                                       \
        (const __attribute__((address_space(1))) unsigned int*)(gp),        \
        (__attribute__((address_space(3))) unsigned int*)(lp), 16, 0, 0)

__device__ inline unsigned short f2bf(float f) {
    union { float f; unsigned int u; } v;
    v.f = f;
    unsigned int r = (v.u + 0x7FFFu + ((v.u >> 16) & 1u)) >> 16;  // RNE
    return (unsigned short)r;
}
__device__ inline float bf2f(unsigned short b) {
    union { unsigned int u; float f; } v;
    v.u = ((unsigned int)b) << 16;
    return v.f;
}

// ---------------- KA: per-chunk histogram | stats partials | Wc pack --------
// blocks [0,sbin): count chunk's dst into LDS hist; write chunk-major row
//   hg[c*NBP + b] — COALESCED (prev round's hg[b*CST+c] was 916K strided-4B
//   writes). 586 chunks (was 147): the scatter pipeline's parallelism was the
//   invariant ~47us cost across rounds 6-10, not the atomic mechanism.
// blocks [sbin, sbin+1024): column sums/sumsq over contiguous row range.
// blocks [sbin+1024, sbin+1088): weight pack (MFMA fragment order).
__global__ __launch_bounds__(256) void kA(const float* __restrict__ x,
                                          float* __restrict__ ws,
                                          const float* __restrict__ Wl,
                                          const float* __restrict__ Wr,
                                          unsigned short* __restrict__ Wc,
                                          const int* __restrict__ ei,
                                          int* __restrict__ hg,
                                          int N, int E, int nb, int sbin) {
    __shared__ float4 sS[4][16];
    __shared__ float4 sQ[4][16];
    __shared__ int hist[NB_MAX];
    int blk = blockIdx.x, t = threadIdx.x;
    if (blk < sbin) {
        int c = blk;
        int e0 = c * SCHUNK;
        for (int b = t; b < NB_MAX; b += 256) hist[b] = 0;
        __syncthreads();
#pragma unroll
        for (int i = 0; i < SCHUNK / 256; i++) {
            int e = e0 + i * 256 + t;
            if (e < E) atomicAdd(&hist[((unsigned)ei[E + e]) >> BSH], 1);
        }
        __syncthreads();
        for (int b = t; b < nb; b += 256) hg[c * NBP + b] = hist[b];
    } else if (blk < sbin + 1024) {
        int sblk = blk - sbin;
        int rpb = (N + 1023) >> 10;        // rows per stats block
        int colg = t & 15, rowi = t >> 4;  // 16 colgroups x 16 rows
        int lane = t & 63, wv = t >> 6;
        const float4* x4 = (const float4*)x;
        float4 s4 = {0.f, 0.f, 0.f, 0.f}, q4 = {0.f, 0.f, 0.f, 0.f};
        int r0 = sblk * rpb;
        for (int i = rowi; i < rpb; i += 16) {
            int r = r0 + i;
            if (r < N) {
                float4 v = x4[r * 16 + colg];
                s4.x += v.x; s4.y += v.y; s4.z += v.z; s4.w += v.w;
                q4.x += v.x * v.x; q4.y += v.y * v.y;
                q4.z += v.z * v.z; q4.w += v.w * v.w;
            }
        }
#pragma unroll
        for (int mk = 16; mk <= 32; mk <<= 1) {
            s4.x += __shfl_xor(s4.x, mk); s4.y += __shfl_xor(s4.y, mk);
            s4.z += __shfl_xor(s4.z, mk); s4.w += __shfl_xor(s4.w, mk);
            q4.x += __shfl_xor(q4.x, mk); q4.y += __shfl_xor(q4.y, mk);
            q4.z += __shfl_xor(q4.z, mk); q4.w += __shfl_xor(q4.w, mk);
        }
        if (lane < 16) { sS[wv][lane] = s4; sQ[wv][lane] = q4; }
        __syncthreads();
        if (t < 16) {
            float4 a = sS[0][t], b4 = sQ[0][t];
#pragma unroll
            for (int w = 1; w < 4; w++) {
                a.x += sS[w][t].x; a.y += sS[w][t].y;
                a.z += sS[w][t].z; a.w += sS[w][t].w;
                b4.x += sQ[w][t].x; b4.y += sQ[w][t].y;
                b4.z += sQ[w][t].z; b4.w += sQ[w][t].w;
            }
            int c0 = t * 4;
            ws[PSOFF + (c0 + 0) * 1024 + sblk] = a.x;
            ws[PSOFF + (c0 + 1) * 1024 + sblk] = a.y;
            ws[PSOFF + (c0 + 2) * 1024 + sblk] = a.z;
            ws[PSOFF + (c0 + 3) * 1024 + sblk] = a.w;
            ws[PQOFF + (c0 + 0) * 1024 + sblk] = b4.x;
            ws[PQOFF + (c0 + 1) * 1024 + sblk] = b4.y;
            ws[PQOFF + (c0 + 2) * 1024 + sblk] = b4.z;
            ws[PQOFF + (c0 + 3) * 1024 + sblk] = b4.w;
        }
    } else {
        int id = (blk - sbin - 1024) * 256 + t;  // 16384 total
        int n = id >> 7, k = id & 127;
        float w = (k < 64) ? Wl[k * HDIM + n] : Wr[(k - 64) * HDIM + n];
        Wc[((k >> 5) * 128 + n) * 32 + (k & 31)] = f2bf(w);
    }
}

// ---------------- KB: BN finalize | per-bucket chunk scan -------------------
// blocks [0,64): column c=blk reduce of 1024 partials -> scale/shift
// blocks [64,64+nsb): one WAVE per bucket — shfl-scan the 586 chunk counts
//   hg[*NBP+b] -> exclusive bases cb[*NBP+b] and bktTot[b]. Strided accesses
//   L2-amortized x16 across the block's 4 adjacent-bucket waves.
__global__ __launch_bounds__(256) void kB(float* __restrict__ ws,
                                          const float* __restrict__ gamma,
                                          const float* __restrict__ beta,
                                          const int* __restrict__ hg,
                                          int* __restrict__ cb,
                                          int* __restrict__ bktTot,
                                          int N, int nb, int sbin) {
    int blk = blockIdx.x, t = threadIdx.x;
    if (blk < 64) {
        __shared__ float r1[256], r2[256];
        const float* pS = ws + PSOFF + blk * 1024;
        const float* pQ = ws + PQOFF + blk * 1024;
        float s = 0.f, q = 0.f;
        for (int j = t; j < 1024; j += 256) { s += pS[j]; q += pQ[j]; }
        r1[t] = s;
        r2[t] = q;
        __syncthreads();
        for (int off = 128; off > 0; off >>= 1) {
            if (t < off) { r1[t] += r1[t + off]; r2[t] += r2[t + off]; }
            __syncthreads();
        }
        if (t == 0) {
            float invN = 1.0f / (float)N;
            float mean = r1[0] * invN;
            float var = r2[0] * invN - mean * mean;
            float sc = rsqrtf(var + BN_EPS) * gamma[blk];
            ws[128 + blk] = sc;
            ws[192 + blk] = beta[blk] - mean * sc;
        }
    } else {
        int lane = t & 63, wv = t >> 6;
        int b = (blk - 64) * 4 + wv;  // bucket for this wave
        if (b >= nb) return;
        int running = 0;
        for (int t0 = 0; t0 < sbin; t0 += 64) {
            int c = t0 + lane;
            int v = (c < sbin) ? hg[c * NBP + b] : 0;
            int incl = v;
#pragma unroll
            for (int off = 1; off < 64; off <<= 1) {
                int tv = __shfl_up(incl, off);
                if (lane >= off) incl += tv;
            }
            if (c < sbin) cb[c * NBP + b] = running + incl - v;
            running += __shfl(incl, 63);
        }
        if (lane == 0) bktTot[b] = running;
    }
}

// ---------------- K3: deterministic scatter | normalize ---------------------
// blocks [0,sbin): scatter chunk c — LDS-local cursors only; write
//   pairs[b*CAP + cb[c][b] + off]. Scatter blocks FIRST (critical path);
//   cbL load coalesced (chunk-major cb).
// blocks [sbin, sbin+2048): xn = bf16(x*scale + shift), float4 grid-stride.
__global__ __launch_bounds__(256) void k3_norm(const float* __restrict__ x,
                                               const float* __restrict__ ws,
                                               unsigned short* __restrict__ xn,
                                               const int* __restrict__ ei,
                                               const int* __restrict__ cb,
                                               int* __restrict__ pairs,
                                               int N, int E, int nb, int sbin) {
    __shared__ int lh[NB_MAX];
    __shared__ int cbL[NB_MAX];
    int blk = blockIdx.x, t = threadIdx.x;
    if (blk < sbin) {
        int c = blk;
        int e0 = c * SCHUNK;
        for (int b = t; b < nb; b += 256) {
            lh[b] = 0;
            cbL[b] = cb[c * NBP + b];  // coalesced
        }
        __syncthreads();
#pragma unroll
        for (int i = 0; i < SCHUNK / 256; i++) {
            int e = e0 + i * 256 + t;
            if (e < E) {
                int src = ei[e];
                int dst = ei[E + e];
                int b = ((unsigned)dst) >> BSH;
                int off = atomicAdd(&lh[b], 1);
                int rel = cbL[b] + off;
                if (rel < CAP) pairs[b * CAP + rel] = (src << BSH) | (dst & 127);
            }
        }
    } else {
        int nblk = blk - sbin;
        const float4* x4 = (const float4*)x;
        ushort4* o4 = (ushort4*)xn;
        int n4 = N * (FEAT / 4);
        int stride = 2048 * 256;
        for (int i = nblk * 256 + t; i < n4; i += stride) {
            int cg = (i & 15) << 2;
            float4 v = x4[i];
            float4 sc = *(const float4*)(ws + 128 + cg);
            float4 sh = *(const float4*)(ws + 192 + cg);
            ushort4 o;
            o.x = f2bf(v.x * sc.x + sh.x);
            o.y = f2bf(v.y * sc.y + sh.y);
            o.z = f2bf(v.z * sc.z + sh.z);
            o.w = f2bf(v.w * sc.w + sh.w);
            o4[i] = o;
        }
    }
}

// ---------------- KDA: fine-group (LDS) + gather + mean ----------------
// Round-2 proven version; bucket b occupies pairs[b*CAP .. b*CAP+bktTot[b]).
// sidx CAP ints (8 KB) -> ~9.8 KB LDS, 4 blocks/CU = 32 waves (max occ).
__global__ __launch_bounds__(512) void kda(const int* __restrict__ pairs,
                                           const int* __restrict__ bktTot,
                                           const unsigned short* __restrict__ xn,
                                           unsigned short* __restrict__ agg, int N) {
    __shared__ int sidx[CAP];
    __shared__ int cnt[128], nstart[128], ncur[128];
    int b = blockIdx.x;
    int base = b << BSH;
    int total = min(bktTot[b], CAP);
    int bs = b * CAP, be = bs + total;
    int t = threadIdx.x;
    int lane = t & 63, wv = t >> 6;   // wv 0..7
    int part = lane & 7, slot = lane >> 3;

    if (t < 128) cnt[t] = 0;
    __syncthreads();
    for (int i = bs + t; i < be; i += 512)
        atomicAdd(&cnt[pairs[i] & 127], 1);
    __syncthreads();
    // wave-0 shuffle scan over the 128 counters
    if (wv == 0) {
        int c0 = cnt[lane], c1 = cnt[64 + lane];
        int a = c0, d = c1;
#pragma unroll
        for (int off = 1; off < 64; off <<= 1) {
            int ta = __shfl_up(a, off);
            int td = __shfl_up(d, off);
            if (lane >= off) { a += ta; d += td; }
        }
        int totA = __shfl(a, 63);
        d += totA;
        nstart[lane] = a - c0;
        ncur[lane] = a - c0;
        nstart[64 + lane] = d - c1;
        ncur[64 + lane] = d - c1;
    }
    __syncthreads();
    for (int i = bs + t; i < be; i += 512) {
        int p = pairs[i];
        int nid = p & 127;
        int pos = atomicAdd(&ncur[nid], 1);
        sidx[pos] = (p >> BSH) << 6;  // src row offset in ushorts
    }
    __syncthreads();

    // gather: wave owns 16 nodes = groups A (slot) and B (slot+8)
    int nA = wv * 16 + slot;
    int nB = nA + 8;
    int stA = nstart[nA], dA = cnt[nA];
    int stB = nstart[nB], dB = cnt[nB];
    float accA[8], accB[8];
#pragma unroll
    for (int j = 0; j < 8; j++) { accA[j] = 0.f; accB[j] = 0.f; }
    bf16x8 vA = {}, vB = {};
    for (int e = 0;; e++) {
        bool pA = e < dA, pB = e < dB;
        if (!__any(pA || pB)) break;
        if (pA) vA = *(const bf16x8*)(xn + sidx[stA + e] + part * 8);
        if (pB) vB = *(const bf16x8*)(xn + sidx[stB + e] + part * 8);
#pragma unroll
        for (int j = 0; j < 8; j++) {
            accA[j] += pA ? bf2f((unsigned short)vA[j]) : 0.f;
            accB[j] += pB ? bf2f((unsigned short)vB[j]) : 0.f;
        }
    }
    int nodeA = base + nA;
    int nodeB = base + nB;
    if (nodeA < N) {
        float dinv = (dA > 0) ? (1.0f / (float)dA) : 0.0f;
        union { bf16x8 v; unsigned short u[8]; } o;
#pragma unroll
        for (int j = 0; j < 8; j++) o.u[j] = f2bf(accA[j] * dinv);
        *(bf16x8*)(agg + (size_t)nodeA * FEAT + part * 8) = o.v;
    }
    if (nodeB < N) {
        float dinv = (dB > 0) ? (1.0f / (float)dB) : 0.0f;
        union { bf16x8 v; unsigned short u[8]; } o;
#pragma unroll
        for (int j = 0; j < 8; j++) o.u[j] = f2bf(accB[j] * dinv);
        *(bf16x8*)(agg + (size_t)nodeB * FEAT + part * 8) = o.v;
    }
}

// ---------------- K5: MFMA GEMM (bf16) + fused head ----------------
// Round-1 proven version: A-tile staged via global_load_lds (width 16),
// XOR-swizzled source + matching read swizzle; register head with 16-lane
// tree reduce. VGPR 64, 3 blocks/CU.
__global__ __launch_bounds__(256, 3) void k5_gemm(
    const unsigned short* __restrict__ agg, const unsigned short* __restrict__ xn,
    const unsigned short* __restrict__ Wc, const float* __restrict__ bl,
    const float* __restrict__ W1, const float* __restrict__ b1,
    const float* __restrict__ W2, const float* __restrict__ b2,
    float* __restrict__ out, int N) {
    __shared__ unsigned char tile[16384];  // [0,8192): agg rows, [8192,16384): xn rows
    __shared__ float hq[64][17];           // cross-ch partial buffer (+1 pad)
    int t = threadIdx.x;
    int lane = t & 63;
    int wv = t >> 6;
    int rh = wv & 1;
    int ch = wv >> 1;
    int c = lane & 15;
    int q = lane >> 4;
    int row0 = blockIdx.x * 64;

    // ---- stage A-tile: 4 global_load_lds per wave, swizzled source ----
    {
        int rrow = t >> 3;  // 0..31 (row within round)
        int sseg = t & 7;
#pragma unroll
        for (int r = 0; r < 2; r++) {
            int row = r * 32 + rrow;               // LDS row 0..63
            int grow = min(row0 + row, N - 1);     // tail clamp (outputs guarded)
            int seg = sseg ^ (row & 7);            // pre-swizzled source segment
            unsigned ldso = (unsigned)(r * 4096 + wv * 1024);  // wave-uniform dest
            GL16(agg + (size_t)grow * 64 + seg * 8, &tile[ldso]);
            GL16(xn + (size_t)grow * 64 + seg * 8, &tile[8192 + ldso]);
        }
    }
    __syncthreads();

    // ---- MFMA main: C[64x128] = [agg|xn] @ Wc ----
    f32x4 acc[2][4];
    f32x4 z = {0.f, 0.f, 0.f, 0.f};
#pragma unroll
    for (int rt = 0; rt < 2; rt++)
#pragma unroll
        for (int nt = 0; nt < 4; nt++) acc[rt][nt] = z;

#pragma unroll
    for (int kt = 0; kt < 4; kt++) {
        bf16x8 bfr[4];
#pragma unroll
        for (int nt = 0; nt < 4; nt++) {
            int col = ch * 64 + nt * 16 + c;
            bfr[nt] = *(const bf16x8*)(Wc + ((size_t)kt * 128 + col) * 32 + q * 8);
        }
        const unsigned char* abase = &tile[(kt < 2) ? 0 : 8192];
        int sg = (kt & 1) * 4 + q;
        bf16x8 af[2];
#pragma unroll
        for (int rt = 0; rt < 2; rt++) {
            int rowL = rh * 32 + rt * 16 + c;
            af[rt] = *(const bf16x8*)&abase[rowL * 128 + ((sg ^ (rowL & 7)) << 4)];
        }
#pragma unroll
        for (int rt = 0; rt < 2; rt++)
#pragma unroll
            for (int nt = 0; nt < 4; nt++)
                acc[rt][nt] = __builtin_amdgcn_mfma_f32_16x16x32_bf16(
                    af[rt], bfr[nt], acc[rt][nt], 0, 0, 0);
    }

    // ---- head: hoist this thread's 4 W1 rows (64 VGPR) + biases ----
    float bln[4];
    float4 w1v[4][4];
#pragma unroll
    for (int nt = 0; nt < 4; nt++) {
        int col = ch * 64 + nt * 16 + c;
        bln[nt] = bl[col];
        const float4* wp = (const float4*)(W1 + col * 16);
#pragma unroll
        for (int qq = 0; qq < 4; qq++) w1v[nt][qq] = wp[qq];
    }
    // lane c ends the tree-reduce owning output m = bitrev4(c)
    int m = ((c & 1) << 3) | ((c & 2) << 1) | ((c & 4) >> 1) | ((c & 8) >> 3);
    float b1v = b1[m];
    float w2x = W2[2 * m];
    float w2y = W2[2 * m + 1];

    float sv[2][4];
#pragma unroll
    for (int rt = 0; rt < 2; rt++) {
#pragma unroll
        for (int r = 0; r < 4; r++) {
            float tp[16];
#pragma unroll
            for (int j = 0; j < 16; j++) tp[j] = 0.f;
#pragma unroll
            for (int nt = 0; nt < 4; nt++) {
                float hv = fmaxf(acc[rt][nt][r] + bln[nt], 0.f);
#pragma unroll
                for (int qq = 0; qq < 4; qq++) {
                    tp[qq * 4 + 0] += hv * w1v[nt][qq].x;
                    tp[qq * 4 + 1] += hv * w1v[nt][qq].y;
                    tp[qq * 4 + 2] += hv * w1v[nt][qq].z;
                    tp[qq * 4 + 3] += hv * w1v[nt][qq].w;
                }
            }
            // tree-exchange reduce over the 16 c-lanes: 15 shuffles
            float u[8];
#pragma unroll
            for (int k = 0; k < 8; k++) {
                float keep = (c & 1) ? tp[k + 8] : tp[k];
                float send = (c & 1) ? tp[k] : tp[k + 8];
                u[k] = keep + __shfl_xor(send, 1);
            }
            float v4[4];
#pragma unroll
            for (int k = 0; k < 4; k++) {
                float keep = (c & 2) ? u[k + 4] : u[k];
                float send = (c & 2) ? u[k] : u[k + 4];
                v4[k] = keep + __shfl_xor(send, 2);
            }
            float w2v[2];
#pragma unroll
            for (int k = 0; k < 2; k++) {
                float keep = (c & 4) ? v4[k + 2] : v4[k];
                float send = (c & 4) ? v4[k] : v4[k + 2];
                w2v[k] = keep + __shfl_xor(send, 4);
            }
            {
                float keep = (c & 8) ? w2v[1] : w2v[0];
                float send = (c & 8) ? w2v[0] : w2v[1];
                sv[rt][r] = keep + __shfl_xor(send, 8);
            }
        }
    }

    // ---- combine ch-halves, apply b1/relu/W2/b2, store ----
    if (ch == 0) {
#pragma unroll
        for (int rt = 0; rt < 2; rt++)
#pragma unroll
            for (int r = 0; r < 4; r++)
                hq[rh * 32 + rt * 16 + q * 4 + r][m] = sv[rt][r];
    }
    __syncthreads();
    if (ch == 1) {
        float b2x = b2[0], b2y = b2[1];
#pragma unroll
        for (int rt = 0; rt < 2; rt++) {
#pragma unroll
            for (int r = 0; r < 4; r++) {
                int row = rh * 32 + rt * 16 + q * 4 + r;
                float tm = sv[rt][r] + hq[row][m] + b1v;
                tm = fmaxf(tm, 0.f);
                float o0 = tm * w2x;
                float o1 = tm * w2y;
#pragma unroll
                for (int mk = 1; mk < 16; mk <<= 1) {
                    o0 += __shfl_xor(o0, mk);
                    o1 += __shfl_xor(o1, mk);
                }
                if (c == 0) {
                    int rowg = row0 + row;
                    if (rowg < N) {
                        out[(size_t)rowg * 2 + 0] = o0 + b2x;
                        out[(size_t)rowg * 2 + 1] = o1 + b2y;
                    }
                }
            }
        }
    }
}

extern "C" void kernel_launch(void* const* d_in, const int* in_sizes, int n_in,
                              void* d_out, int out_size, void* d_ws, size_t ws_size,
                              hipStream_t stream) {
    const float* x = (const float*)d_in[0];
    const int* ei = (const int*)d_in[1];
    const float* gamma = (const float*)d_in[6];
    const float* beta = (const float*)d_in[7];
    const float* Wl = (const float*)d_in[8];
    const float* bl = (const float*)d_in[9];
    const float* Wr = (const float*)d_in[10];
    const float* W1 = (const float*)d_in[11];
    const float* b1 = (const float*)d_in[12];
    const float* W2 = (const float*)d_in[13];
    const float* b2 = (const float*)d_in[14];

    int N = in_sizes[0] / FEAT;   // 100000
    int E = in_sizes[1] / 2;      // 1200000
    int nb = (N + 127) >> BSH;    // 782 buckets
    int sbin = (E + SCHUNK - 1) / SCHUNK;  // 586 chunks
    int nsb = (nb + 3) / 4;                // scan blocks (4 waves each)

    float* ws = (float*)d_ws;
    int* wsi = (int*)d_ws;
    int aggOff = XNOFF + N * 32;             // N*32 floats (bf16 agg)
    int hgOff = aggOff + N * 32;             // CMAX*NBP ints
    int cbOff = hgOff + CMAX * NBP;          // CMAX*NBP ints
    int btOff = cbOff + CMAX * NBP;          // NB_MAX ints
    int pairsOff = (btOff + NB_MAX + 63) & ~63;  // nb*CAP ints

    unsigned short* xnp = (unsigned short*)(ws + XNOFF);
    unsigned short* aggp = (unsigned short*)(ws + aggOff);
    unsigned short* wcp = (unsigned short*)(ws + WCOFF);
    int* hg = wsi + hgOff;
    int* cb = wsi + cbOff;
    int* bktTot = wsi + btOff;
    int* pairs = wsi + pairsOff;

    float* out = (float*)d_out;

    hipLaunchKernelGGL(kA, dim3(sbin + 1088), dim3(256), 0, stream,
                       x, ws, Wl, Wr, wcp, ei, hg, N, E, nb, sbin);
    hipLaunchKernelGGL(kB, dim3(64 + nsb), dim3(256), 0, stream,
                       ws, gamma, beta, hg, cb, bktTot, N, nb, sbin);
    hipLaunchKernelGGL(k3_norm, dim3(sbin + 2048), dim3(256), 0, stream,
                       x, ws, xnp, ei, cb, pairs, N, E, nb, sbin);
    hipLaunchKernelGGL(kda, dim3(nb), dim3(512), 0, stream,
                       pairs, bktTot, xnp, aggp, N);
    hipLaunchKernelGGL(k5_gemm, dim3((N + 63) / 64), dim3(256), 0, stream,
                       aggp, xnp, wcp, bl, W1, b1, W2, b2, out, N);
}

// Round 12
// 237.685 us; speedup vs baseline: 1.1961x; 1.0493x over previous
//
#include <hip/hip_runtime.h>

#define FEAT 64
#define HDIM 128
#define BN_EPS 1e-5f

#define BSH 7          // 128 nodes per bucket
#define NB_MAX 1024    // max buckets (N <= 131072)
#define NBP 800        // padded bucket stride (chunk-major hg/cbw rows)
#define SCHUNK 2048    // edges per chunk (586 chunks)
#define CMAX 1024      // max chunks (LDS seg arrays sized to this)
#define CAP 2048       // collected edges per bucket (mean 1536, +13 sigma)

// ws float offsets
#define PSOFF 1280     // column-major stats partials: pS[col][1024]
#define PQOFF (PSOFF + 65536)
#define WCOFF (PQOFF + 65536)
#define XNOFF (WCOFF + 8192)

typedef __attribute__((ext_vector_type(8))) short bf16x8;
typedef __attribute__((ext_vector_type(4))) float f32x4;

// async global->LDS, 16B per lane; LDS dest must be wave-uniform base
#define GL16(gp, lp)                                                        \
    __builtin_amdgcn_global_load_lds(                                       \
        (const __attribute__((address_space(1))) unsigned int*)(gp),        \
        (__attribute__((address_space(3))) unsigned int*)(lp), 16, 0, 0)

__device__ inline unsigned short f2bf(float f) {
    union { float f; unsigned int u; } v;
    v.f = f;
    unsigned int r = (v.u + 0x7FFFu + ((v.u >> 16) & 1u)) >> 16;  // RNE
    return (unsigned short)r;
}
__device__ inline float bf2f(unsigned short b) {
    union { unsigned int u; float f; } v;
    v.u = ((unsigned int)b) << 16;
    return v.f;
}

// ---------------- KA: chunk-local edge sort | stats partials | Wc pack ------
// blocks [0,sbin): hist -> in-block scan -> LDS scatter -> stream the SORTED
//   chunk to pairs[c*2048..] with int4 stores into an EXCLUSIVE 8KB region.
//   Eliminates the cross-XCD partial-line store sharing that pinned every
//   prior scatter design at ~40us (5 designs, invariant cost). Also emits
//   hg[c][b] (counts) and cbw[c][b] (within-chunk bases), coalesced.
// blocks [sbin, sbin+1024): column sums/sumsq over contiguous row range.
// blocks [sbin+1024, sbin+1088): weight pack (MFMA fragment order).
__global__ __launch_bounds__(256) void kA(const float* __restrict__ x,
                                          float* __restrict__ ws,
                                          const float* __restrict__ Wl,
                                          const float* __restrict__ Wr,
                                          unsigned short* __restrict__ Wc,
                                          const int* __restrict__ ei,
                                          int* __restrict__ hg,
                                          int* __restrict__ cbw,
                                          int* __restrict__ pairs,
                                          int N, int E, int nb, int sbin) {
    __shared__ float4 sS[4][16];
    __shared__ float4 sQ[4][16];
    __shared__ int hist[NB_MAX];
    __shared__ int basev[NB_MAX];
    __shared__ int tsum[256];
    __shared__ int sidxL[SCHUNK];
    int blk = blockIdx.x, t = threadIdx.x;
    if (blk < sbin) {
        int c = blk;
        int e0 = c * SCHUNK;
        for (int b = t; b < NB_MAX; b += 256) hist[b] = 0;
        __syncthreads();
#pragma unroll
        for (int i = 0; i < SCHUNK / 256; i++) {
            int e = e0 + i * 256 + t;
            if (e < E) atomicAdd(&hist[((unsigned)ei[E + e]) >> BSH], 1);
        }
        __syncthreads();
        // exclusive scan over the 1024 counters: thread t owns [4t, 4t+4)
        int b0 = t * 4;
        int h0 = hist[b0], h1 = hist[b0 + 1], h2 = hist[b0 + 2], h3 = hist[b0 + 3];
        int s = h0 + h1 + h2 + h3;
        tsum[t] = s;
        __syncthreads();
        int v = s;
        for (int off = 1; off < 256; off <<= 1) {
            int add = (t >= off) ? tsum[t - off] : 0;
            __syncthreads();
            v += add;
            tsum[t] = v;
            __syncthreads();
        }
        int run = v - s;
        basev[b0] = run; run += h0;
        basev[b0 + 1] = run; run += h1;
        basev[b0 + 2] = run; run += h2;
        basev[b0 + 3] = run;
        __syncthreads();
        // emit counts + within-chunk bases (coalesced)
        for (int b = t; b < nb; b += 256) {
            hg[c * NBP + b] = hist[b];
            cbw[c * NBP + b] = basev[b];
        }
        __syncthreads();
        // pass2: scatter edges into LDS, grouped by bucket (basev = cursors)
#pragma unroll
        for (int i = 0; i < SCHUNK / 256; i++) {
            int e = e0 + i * 256 + t;
            if (e < E) {
                int src = ei[e];
                int dst = ei[E + e];
                int b = ((unsigned)dst) >> BSH;
                int pos = atomicAdd(&basev[b], 1);
                sidxL[pos] = (src << BSH) | (dst & 127);
            }
        }
        __syncthreads();
        // stream sorted chunk out: full-line, exclusive-region int4 stores
        const int4* sl4 = (const int4*)sidxL;
        int4* pg4 = (int4*)(pairs + (size_t)c * SCHUNK);
#pragma unroll
        for (int i = 0; i < SCHUNK / 1024; i++) pg4[i * 256 + t] = sl4[i * 256 + t];
    } else if (blk < sbin + 1024) {
        int sblk = blk - sbin;
        int rpb = (N + 1023) >> 10;        // rows per stats block
        int colg = t & 15, rowi = t >> 4;  // 16 colgroups x 16 rows
        int lane = t & 63, wv = t >> 6;
        const float4* x4 = (const float4*)x;
        float4 s4 = {0.f, 0.f, 0.f, 0.f}, q4 = {0.f, 0.f, 0.f, 0.f};
        int r0 = sblk * rpb;
        for (int i = rowi; i < rpb; i += 16) {
            int r = r0 + i;
            if (r < N) {
                float4 v = x4[r * 16 + colg];
                s4.x += v.x; s4.y += v.y; s4.z += v.z; s4.w += v.w;
                q4.x += v.x * v.x; q4.y += v.y * v.y;
                q4.z += v.z * v.z; q4.w += v.w * v.w;
            }
        }
#pragma unroll
        for (int mk = 16; mk <= 32; mk <<= 1) {
            s4.x += __shfl_xor(s4.x, mk); s4.y += __shfl_xor(s4.y, mk);
            s4.z += __shfl_xor(s4.z, mk); s4.w += __shfl_xor(s4.w, mk);
            q4.x += __shfl_xor(q4.x, mk); q4.y += __shfl_xor(q4.y, mk);
            q4.z += __shfl_xor(q4.z, mk); q4.w += __shfl_xor(q4.w, mk);
        }
        if (lane < 16) { sS[wv][lane] = s4; sQ[wv][lane] = q4; }
        __syncthreads();
        if (t < 16) {
            float4 a = sS[0][t], b4 = sQ[0][t];
#pragma unroll
            for (int w = 1; w < 4; w++) {
                a.x += sS[w][t].x; a.y += sS[w][t].y;
                a.z += sS[w][t].z; a.w += sS[w][t].w;
                b4.x += sQ[w][t].x; b4.y += sQ[w][t].y;
                b4.z += sQ[w][t].z; b4.w += sQ[w][t].w;
            }
            int c0 = t * 4;
            ws[PSOFF + (c0 + 0) * 1024 + sblk] = a.x;
            ws[PSOFF + (c0 + 1) * 1024 + sblk] = a.y;
            ws[PSOFF + (c0 + 2) * 1024 + sblk] = a.z;
            ws[PSOFF + (c0 + 3) * 1024 + sblk] = a.w;
            ws[PQOFF + (c0 + 0) * 1024 + sblk] = b4.x;
            ws[PQOFF + (c0 + 1) * 1024 + sblk] = b4.y;
            ws[PQOFF + (c0 + 2) * 1024 + sblk] = b4.z;
            ws[PQOFF + (c0 + 3) * 1024 + sblk] = b4.w;
        }
    } else {
        int id = (blk - sbin - 1024) * 256 + t;  // 16384 total
        int n = id >> 7, k = id & 127;
        float w = (k < 64) ? Wl[k * HDIM + n] : Wr[(k - 64) * HDIM + n];
        Wc[((k >> 5) * 128 + n) * 32 + (k & 31)] = f2bf(w);
    }
}

// ---------------- KB: BN finalize (64 blocks, one column each) --------------
__global__ __launch_bounds__(256) void kB(float* __restrict__ ws,
                                          const float* __restrict__ gamma,
                                          const float* __restrict__ beta, int N) {
    __shared__ float r1[256], r2[256];
    int blk = blockIdx.x, t = threadIdx.x;
    const float* pS = ws + PSOFF + blk * 1024;
    const float* pQ = ws + PQOFF + blk * 1024;
    float s = 0.f, q = 0.f;
    for (int j = t; j < 1024; j += 256) { s += pS[j]; q += pQ[j]; }
    r1[t] = s;
    r2[t] = q;
    __syncthreads();
    for (int off = 128; off > 0; off >>= 1) {
        if (t < off) { r1[t] += r1[t + off]; r2[t] += r2[t + off]; }
        __syncthreads();
    }
    if (t == 0) {
        float invN = 1.0f / (float)N;
        float mean = r1[0] * invN;
        float var = r2[0] * invN - mean * mean;
        float sc = rsqrtf(var + BN_EPS) * gamma[blk];
        ws[128 + blk] = sc;
        ws[192 + blk] = beta[blk] - mean * sc;
    }
}

// ---------------- K3: xn = bf16(x*scale + shift) ----------------
__global__ __launch_bounds__(256) void k3_norm(const float* __restrict__ x,
                                               const float* __restrict__ ws,
                                               unsigned short* __restrict__ xn, int N) {
    const float4* x4 = (const float4*)x;
    ushort4* o4 = (ushort4*)xn;
    int n4 = N * (FEAT / 4);
    int stride = gridDim.x * blockDim.x;
    for (int i = blockIdx.x * blockDim.x + threadIdx.x; i < n4; i += stride) {
        int cg = (i & 15) << 2;
        float4 v = x4[i];
        float4 sc = *(const float4*)(ws + 128 + cg);
        float4 sh = *(const float4*)(ws + 192 + cg);
        ushort4 o;
        o.x = f2bf(v.x * sc.x + sh.x);
        o.y = f2bf(v.y * sc.y + sh.y);
        o.z = f2bf(v.z * sc.z + sh.z);
        o.w = f2bf(v.w * sc.w + sh.w);
        o4[i] = o;
    }
}

// ---------------- KDA: collect (read-side permutation) + group + gather -----
// Collect: scan the per-chunk lengths hg[*][b] (block scan over 1024-padded),
// then pull this bucket's edges from the per-chunk sorted runs (scattered 4B
// READS — no cross-XCD write sharing) into LDS srcb. Then the proven
// group+gather runs unchanged on srcb.
__global__ __launch_bounds__(512) void kda(const int* __restrict__ pairs,
                                           const int* __restrict__ hg,
                                           const int* __restrict__ cbw,
                                           const unsigned short* __restrict__ xn,
                                           unsigned short* __restrict__ agg,
                                           int N, int sbin) {
    __shared__ int hseg[CMAX], wseg[CMAX], oseg[CMAX];
    __shared__ int scanb[512];
    __shared__ int srcb[CAP];
    __shared__ int sidx[CAP];
    __shared__ int cnt[128], nstart[128], ncur[128];
    int b = blockIdx.x;
    int base = b << BSH;
    int t = threadIdx.x;
    int lane = t & 63, wv = t >> 6;   // wv 0..7
    int part = lane & 7, slot = lane >> 3;

    // load this bucket's per-chunk lengths and within-chunk bases
    for (int c = t; c < CMAX; c += 512) {
        hseg[c] = (c < sbin) ? hg[c * NBP + b] : 0;
        wseg[c] = (c < sbin) ? cbw[c * NBP + b] : 0;
    }
    __syncthreads();
    // exclusive scan of lengths: thread t owns c = 2t, 2t+1
    int c0 = 2 * t;
    int ha = hseg[c0], hb2 = hseg[c0 + 1];
    int s = ha + hb2;
    scanb[t] = s;
    __syncthreads();
    int v = s;
    for (int off = 1; off < 512; off <<= 1) {
        int add = (t >= off) ? scanb[t - off] : 0;
        __syncthreads();
        v += add;
        scanb[t] = v;
        __syncthreads();
    }
    int eb = v - s;
    oseg[c0] = eb;
    oseg[c0 + 1] = eb + ha;
    __syncthreads();
    int total = min(scanb[511], CAP);
    // collect: each thread copies its two chunks' runs
#pragma unroll
    for (int j = 0; j < 2; j++) {
        int c = c0 + j;
        int h = hseg[c], w = wseg[c], o = oseg[c];
        const int* pg = pairs + (size_t)c * SCHUNK + w;
        for (int k = 0; k < h; k++) {
            int p = o + k;
            if (p < CAP) srcb[p] = pg[k];
        }
    }
    __syncthreads();

    // ---- proven grouping: count nodes, scan, scatter into sidx ----
    if (t < 128) cnt[t] = 0;
    __syncthreads();
    for (int i = t; i < total; i += 512)
        atomicAdd(&cnt[srcb[i] & 127], 1);
    __syncthreads();
    if (wv == 0) {
        int cc0 = cnt[lane], cc1 = cnt[64 + lane];
        int a = cc0, d = cc1;
#pragma unroll
        for (int off = 1; off < 64; off <<= 1) {
            int ta = __shfl_up(a, off);
            int td = __shfl_up(d, off);
            if (lane >= off) { a += ta; d += td; }
        }
        int totA = __shfl(a, 63);
        d += totA;
        nstart[lane] = a - cc0;
        ncur[lane] = a - cc0;
        nstart[64 + lane] = d - cc1;
        ncur[64 + lane] = d - cc1;
    }
    __syncthreads();
    for (int i = t; i < total; i += 512) {
        int p = srcb[i];
        int nid = p & 127;
        int pos = atomicAdd(&ncur[nid], 1);
        sidx[pos] = (p >> BSH) << 6;  // src row offset in ushorts
    }
    __syncthreads();

    // ---- gather: wave owns 16 nodes = groups A (slot) and B (slot+8) ----
    int nA = wv * 16 + slot;
    int nB = nA + 8;
    int stA = nstart[nA], dA = cnt[nA];
    int stB = nstart[nB], dB = cnt[nB];
    float accA[8], accB[8];
#pragma unroll
    for (int j = 0; j < 8; j++) { accA[j] = 0.f; accB[j] = 0.f; }
    bf16x8 vA = {}, vB = {};
    for (int e = 0;; e++) {
        bool pA = e < dA, pB = e < dB;
        if (!__any(pA || pB)) break;
        if (pA) vA = *(const bf16x8*)(xn + sidx[stA + e] + part * 8);
        if (pB) vB = *(const bf16x8*)(xn + sidx[stB + e] + part * 8);
#pragma unroll
        for (int j = 0; j < 8; j++) {
            accA[j] += pA ? bf2f((unsigned short)vA[j]) : 0.f;
            accB[j] += pB ? bf2f((unsigned short)vB[j]) : 0.f;
        }
    }
    int nodeA = base + nA;
    int nodeB = base + nB;
    if (nodeA < N) {
        float dinv = (dA > 0) ? (1.0f / (float)dA) : 0.0f;
        union { bf16x8 v; unsigned short u[8]; } o;
#pragma unroll
        for (int j = 0; j < 8; j++) o.u[j] = f2bf(accA[j] * dinv);
        *(bf16x8*)(agg + (size_t)nodeA * FEAT + part * 8) = o.v;
    }
    if (nodeB < N) {
        float dinv = (dB > 0) ? (1.0f / (float)dB) : 0.0f;
        union { bf16x8 v; unsigned short u[8]; } o;
#pragma unroll
        for (int j = 0; j < 8; j++) o.u[j] = f2bf(accB[j] * dinv);
        *(bf16x8*)(agg + (size_t)nodeB * FEAT + part * 8) = o.v;
    }
}

// ---------------- K5: MFMA GEMM (bf16) + fused head ----------------
// Round-1 proven version: A-tile staged via global_load_lds (width 16),
// XOR-swizzled source + matching read swizzle; register head with 16-lane
// tree reduce. VGPR 64, 3 blocks/CU.
__global__ __launch_bounds__(256, 3) void k5_gemm(
    const unsigned short* __restrict__ agg, const unsigned short* __restrict__ xn,
    const unsigned short* __restrict__ Wc, const float* __restrict__ bl,
    const float* __restrict__ W1, const float* __restrict__ b1,
    const float* __restrict__ W2, const float* __restrict__ b2,
    float* __restrict__ out, int N) {
    __shared__ unsigned char tile[16384];  // [0,8192): agg rows, [8192,16384): xn rows
    __shared__ float hq[64][17];           // cross-ch partial buffer (+1 pad)
    int t = threadIdx.x;
    int lane = t & 63;
    int wv = t >> 6;
    int rh = wv & 1;
    int ch = wv >> 1;
    int c = lane & 15;
    int q = lane >> 4;
    int row0 = blockIdx.x * 64;

    // ---- stage A-tile: 4 global_load_lds per wave, swizzled source ----
    {
        int rrow = t >> 3;  // 0..31 (row within round)
        int sseg = t & 7;
#pragma unroll
        for (int r = 0; r < 2; r++) {
            int row = r * 32 + rrow;               // LDS row 0..63
            int grow = min(row0 + row, N - 1);     // tail clamp (outputs guarded)
            int seg = sseg ^ (row & 7);            // pre-swizzled source segment
            unsigned ldso = (unsigned)(r * 4096 + wv * 1024);  // wave-uniform dest
            GL16(agg + (size_t)grow * 64 + seg * 8, &tile[ldso]);
            GL16(xn + (size_t)grow * 64 + seg * 8, &tile[8192 + ldso]);
        }
    }
    __syncthreads();

    // ---- MFMA main: C[64x128] = [agg|xn] @ Wc ----
    f32x4 acc[2][4];
    f32x4 z = {0.f, 0.f, 0.f, 0.f};
#pragma unroll
    for (int rt = 0; rt < 2; rt++)
#pragma unroll
        for (int nt = 0; nt < 4; nt++) acc[rt][nt] = z;

#pragma unroll
    for (int kt = 0; kt < 4; kt++) {
        bf16x8 bfr[4];
#pragma unroll
        for (int nt = 0; nt < 4; nt++) {
            int col = ch * 64 + nt * 16 + c;
            bfr[nt] = *(const bf16x8*)(Wc + ((size_t)kt * 128 + col) * 32 + q * 8);
        }
        const unsigned char* abase = &tile[(kt < 2) ? 0 : 8192];
        int sg = (kt & 1) * 4 + q;
        bf16x8 af[2];
#pragma unroll
        for (int rt = 0; rt < 2; rt++) {
            int rowL = rh * 32 + rt * 16 + c;
            af[rt] = *(const bf16x8*)&abase[rowL * 128 + ((sg ^ (rowL & 7)) << 4)];
        }
#pragma unroll
        for (int rt = 0; rt < 2; rt++)
#pragma unroll
            for (int nt = 0; nt < 4; nt++)
                acc[rt][nt] = __builtin_amdgcn_mfma_f32_16x16x32_bf16(
                    af[rt], bfr[nt], acc[rt][nt], 0, 0, 0);
    }

    // ---- head: hoist this thread's 4 W1 rows (64 VGPR) + biases ----
    float bln[4];
    float4 w1v[4][4];
#pragma unroll
    for (int nt = 0; nt < 4; nt++) {
        int col = ch * 64 + nt * 16 + c;
        bln[nt] = bl[col];
        const float4* wp = (const float4*)(W1 + col * 16);
#pragma unroll
        for (int qq = 0; qq < 4; qq++) w1v[nt][qq] = wp[qq];
    }
    // lane c ends the tree-reduce owning output m = bitrev4(c)
    int m = ((c & 1) << 3) | ((c & 2) << 1) | ((c & 4) >> 1) | ((c & 8) >> 3);
    float b1v = b1[m];
    float w2x = W2[2 * m];
    float w2y = W2[2 * m + 1];

    float sv[2][4];
#pragma unroll
    for (int rt = 0; rt < 2; rt++) {
#pragma unroll
        for (int r = 0; r < 4; r++) {
            float tp[16];
#pragma unroll
            for (int j = 0; j < 16; j++) tp[j] = 0.f;
#pragma unroll
            for (int nt = 0; nt < 4; nt++) {
                float hv = fmaxf(acc[rt][nt][r] + bln[nt], 0.f);
#pragma unroll
                for (int qq = 0; qq < 4; qq++) {
                    tp[qq * 4 + 0] += hv * w1v[nt][qq].x;
                    tp[qq * 4 + 1] += hv * w1v[nt][qq].y;
                    tp[qq * 4 + 2] += hv * w1v[nt][qq].z;
                    tp[qq * 4 + 3] += hv * w1v[nt][qq].w;
                }
            }
            // tree-exchange reduce over the 16 c-lanes: 15 shuffles
            float u[8];
#pragma unroll
            for (int k = 0; k < 8; k++) {
                float keep = (c & 1) ? tp[k + 8] : tp[k];
                float send = (c & 1) ? tp[k] : tp[k + 8];
                u[k] = keep + __shfl_xor(send, 1);
            }
            float v4[4];
#pragma unroll
            for (int k = 0; k < 4; k++) {
                float keep = (c & 2) ? u[k + 4] : u[k];
                float send = (c & 2) ? u[k] : u[k + 4];
                v4[k] = keep + __shfl_xor(send, 2);
            }
            float w2v[2];
#pragma unroll
            for (int k = 0; k < 2; k++) {
                float keep = (c & 4) ? v4[k + 2] : v4[k];
                float send = (c & 4) ? v4[k] : v4[k + 2];
                w2v[k] = keep + __shfl_xor(send, 4);
            }
            {
                float keep = (c & 8) ? w2v[1] : w2v[0];
                float send = (c & 8) ? w2v[0] : w2v[1];
                sv[rt][r] = keep + __shfl_xor(send, 8);
            }
        }
    }

    // ---- combine ch-halves, apply b1/relu/W2/b2, store ----
    if (ch == 0) {
#pragma unroll
        for (int rt = 0; rt < 2; rt++)
#pragma unroll
            for (int r = 0; r < 4; r++)
                hq[rh * 32 + rt * 16 + q * 4 + r][m] = sv[rt][r];
    }
    __syncthreads();
    if (ch == 1) {
        float b2x = b2[0], b2y = b2[1];
#pragma unroll
        for (int rt = 0; rt < 2; rt++) {
#pragma unroll
            for (int r = 0; r < 4; r++) {
                int row = rh * 32 + rt * 16 + q * 4 + r;
                float tm = sv[rt][r] + hq[row][m] + b1v;
                tm = fmaxf(tm, 0.f);
                float o0 = tm * w2x;
                float o1 = tm * w2y;
#pragma unroll
                for (int mk = 1; mk < 16; mk <<= 1) {
                    o0 += __shfl_xor(o0, mk);
                    o1 += __shfl_xor(o1, mk);
                }
                if (c == 0) {
                    int rowg = row0 + row;
                    if (rowg < N) {
                        out[(size_t)rowg * 2 + 0] = o0 + b2x;
                        out[(size_t)rowg * 2 + 1] = o1 + b2y;
                    }
                }
            }
        }
    }
}

extern "C" void kernel_launch(void* const* d_in, const int* in_sizes, int n_in,
                              void* d_out, int out_size, void* d_ws, size_t ws_size,
                              hipStream_t stream) {
    const float* x = (const float*)d_in[0];
    const int* ei = (const int*)d_in[1];
    const float* gamma = (const float*)d_in[6];
    const float* beta = (const float*)d_in[7];
    const float* Wl = (const float*)d_in[8];
    const float* bl = (const float*)d_in[9];
    const float* Wr = (const float*)d_in[10];
    const float* W1 = (const float*)d_in[11];
    const float* b1 = (const float*)d_in[12];
    const float* W2 = (const float*)d_in[13];
    const float* b2 = (const float*)d_in[14];

    int N = in_sizes[0] / FEAT;   // 100000
    int E = in_sizes[1] / 2;      // 1200000
    int nb = (N + 127) >> BSH;    // 782 buckets
    int sbin = (E + SCHUNK - 1) / SCHUNK;  // 586 chunks

    float* ws = (float*)d_ws;
    int* wsi = (int*)d_ws;
    int aggOff = XNOFF + N * 32;             // N*32 floats (bf16 agg)
    int hgOff = aggOff + N * 32;             // CMAX*NBP ints
    int cbOff = hgOff + CMAX * NBP;          // CMAX*NBP ints
    int pairsOff = (cbOff + CMAX * NBP + 63) & ~63;  // sbin*SCHUNK ints

    unsigned short* xnp = (unsigned short*)(ws + XNOFF);
    unsigned short* aggp = (unsigned short*)(ws + aggOff);
    unsigned short* wcp = (unsigned short*)(ws + WCOFF);
    int* hg = wsi + hgOff;
    int* cbw = wsi + cbOff;
    int* pairs = wsi + pairsOff;

    float* out = (float*)d_out;

    hipLaunchKernelGGL(kA, dim3(sbin + 1088), dim3(256), 0, stream,
                       x, ws, Wl, Wr, wcp, ei, hg, cbw, pairs, N, E, nb, sbin);
    hipLaunchKernelGGL(kB, dim3(64), dim3(256), 0, stream, ws, gamma, beta, N);
    hipLaunchKernelGGL(k3_norm, dim3(2048), dim3(256), 0, stream, x, ws, xnp, N);
    hipLaunchKernelGGL(kda, dim3(nb), dim3(512), 0, stream,
                       pairs, hg, cbw, xnp, aggp, N, sbin);
    hipLaunchKernelGGL(k5_gemm, dim3((N + 63) / 64), dim3(256), 0, stream,
                       aggp, xnp, wcp, bl, W1, b1, W2, b2, out, N);
}